// Round 1
// 428.141 us; speedup vs baseline: 1.0146x; 1.0146x over previous
//
#include <hip/hip_runtime.h>
#include <cstdio>
#include <cstdint>

#define N_NODES 50000
#define N_EDGES 500000
#define EMB 128
#define BOND 64
#define NGRAPH 256
#define NB_SCAN ((N_NODES + 255) / 256)   // 196 scan blocks
#define NSTRIP (N_NODES / 16)             // 3125 exact 16-node strips
#define ESTRIP (N_EDGES / 16)             // 31250 exact 16-edge strips

typedef short bf16x8 __attribute__((ext_vector_type(8)));   // 8 bf16 (4 VGPRs)
typedef float f32x4  __attribute__((ext_vector_type(4)));

__device__ __forceinline__ unsigned short f2bf(float v){
  unsigned u = __float_as_uint(v);
  unsigned r = (u + 0x7fffu + ((u >> 16) & 1u)) >> 16;  // RNE
  return (unsigned short)r;
}
__device__ __forceinline__ float bf2f(unsigned short u){
  return __uint_as_float(((unsigned)u) << 16);
}
__device__ __forceinline__ unsigned short brelu(unsigned short u){
  return (u & 0x8000u) ? (unsigned short)0 : u;   // bf16 relu: sign bit -> 0
}

// ---------------------------------------------------------------------------
// Channel permutation: node/edge embedding rows are stored in MFMA-fragment
// order. Stored position p holds TRUE channel sigma(p) = (p&7)*16 + (p>>3).
// agg_kernel (elementwise mul + per-channel sum + residual) is permutation-
// invariant; the MLP compensates by permuting W1's K dimension in prep_w.
// This removes the LDS C-fragment transpose from both embedding GEMMs.
// ---------------------------------------------------------------------------

// weight prep: fragment-linear bf16 for Wa, W1 (K-permuted), W2, Wb
__global__ void prep_w(const float* __restrict__ Wa, const float* __restrict__ W1,
                       const float* __restrict__ W2, const float* __restrict__ Wb,
                       unsigned short* __restrict__ wabf, unsigned short* __restrict__ w1bf,
                       unsigned short* __restrict__ w2bf, unsigned short* __restrict__ wbbf)
{
  int i = blockIdx.x * 256 + threadIdx.x;
  if (i < 40960){
    int i2 = i & 16383;
    int j = i2 & 7, lb = (i2 >> 3) & 63, kc = (i2 >> 9) & 3, tn = i2 >> 11;
    int lm = lb & 15, q = lb >> 4;
    int row = tn * 16 + lm, col = kc * 32 + q * 8 + j;
    if (i < 16384){
      wabf[i] = f2bf(Wa[row * EMB + col]);                 // K = raw atom dim, unpermuted
    } else if (i < 32768){
      int pcol = j * 16 + kc * 4 + q;                      // sigma(col): match permuted node layout
      w1bf[i2] = f2bf(W1[row * EMB + pcol]);
    } else {
      w2bf[i2] = f2bf(W2[row * EMB + col]);                // h1 is standard layout; tn in [0,4)
    }
  } else if (i < 49152){
    int i2 = i - 40960;                                    // Wb: [8 tn][2 kc][64 l][8 j]
    int j = i2 & 7, l = (i2 >> 3) & 63, kc = (i2 >> 9) & 1, tn = i2 >> 10;
    int lm = l & 15, q = l >> 4;
    wbbf[i2] = f2bf(Wb[(tn * 16 + lm) * BOND + kc * 32 + q * 8 + j]);
  }
}

// ---------------- bf16 MFMA node-embedding GEMM, direct fragment store ----------------
__global__ __launch_bounds__(256) void node_gemm_mfma(const float* __restrict__ x,
    const unsigned short* __restrict__ wabf, const float* __restrict__ ba,
    unsigned short* __restrict__ out)
{
  const int t = threadIdx.x;
  const int wv = t >> 6, l = t & 63;
  const int lm = l & 15, q = l >> 4;
  union U8 { bf16x8 v; unsigned short s[8]; };
  const int strip = blockIdx.x * 4 + wv;
  if (strip >= NSTRIP) return;
  const long n0 = (long)strip * 16;

  bf16x8 a[4];
  #pragma unroll
  for (int kc = 0; kc < 4; kc++){
    const float* ap = x + (n0 + lm) * (long)EMB + kc * 32 + q * 8;
    float4 x0 = *(const float4*)ap;
    float4 x1 = *(const float4*)(ap + 4);
    U8 u;
    u.s[0] = f2bf(x0.x); u.s[1] = f2bf(x0.y); u.s[2] = f2bf(x0.z); u.s[3] = f2bf(x0.w);
    u.s[4] = f2bf(x1.x); u.s[5] = f2bf(x1.y); u.s[6] = f2bf(x1.z); u.s[7] = f2bf(x1.w);
    a[kc] = u.v;
  }
  float biasv[8];
  #pragma unroll
  for (int tn = 0; tn < 8; tn++) biasv[tn] = ba[tn * 16 + lm];

  f32x4 acc[8];
  #pragma unroll
  for (int tn = 0; tn < 8; tn++) acc[tn] = (f32x4){0.f, 0.f, 0.f, 0.f};
  #pragma unroll
  for (int kc = 0; kc < 4; kc++){
    #pragma unroll
    for (int tn = 0; tn < 8; tn++){
      bf16x8 bf = *(const bf16x8*)(wabf + (size_t)((tn * 4 + kc) * 64 + l) * 8);
      acc[tn] = __builtin_amdgcn_mfma_f32_16x16x32_bf16(a[kc], bf, acc[tn], 0, 0, 0);
    }
  }
  // direct permuted store: row n0+q*4+i, positions lm*8+tn hold channel tn*16+lm
  #pragma unroll
  for (int i = 0; i < 4; i++){
    U8 o;
    #pragma unroll
    for (int tn = 0; tn < 8; tn++) o.s[tn] = f2bf(acc[tn][i] + biasv[tn]);
    *(bf16x8*)(out + (n0 + q * 4 + i) * (long)EMB + lm * 8) = o.v;
  }
}

// ---------------- bf16 MFMA edge GEMM, CSR-gather, direct fragment store ----------------
// R8: LDS C-transform removed entirely (permuted row layout). 256-thread blocks,
// no LDS -> occupancy limited only by VGPRs; zero bank conflicts, zero lgkm waits.
__global__ __launch_bounds__(256) void edge_gemm_mfma(
    const float* __restrict__ attr, const unsigned short* __restrict__ wbbf,
    const float* __restrict__ bb, const int2* __restrict__ cse,
    unsigned short* __restrict__ eemb)
{
  const int t = threadIdx.x;
  const int l = t & 63;
  const int lm = l & 15, q = l >> 4;
  union U8 { bf16x8 v; unsigned short s[8]; };

  bf16x8 bfrag[8][2];
  float bias[8];
  #pragma unroll
  for (int tn = 0; tn < 8; tn++){
    bias[tn] = bb[tn * 16 + lm];
    #pragma unroll
    for (int kc = 0; kc < 2; kc++)
      bfrag[tn][kc] = *(const bf16x8*)(wbbf + (size_t)((tn * 2 + kc) * 64 + l) * 8);
  }

  const long wid = (long)blockIdx.x * 4 + (t >> 6);
  const long stride = (long)gridDim.x * 4 * 16;
  for (long p0 = wid * 16; p0 < N_EDGES; p0 += stride){
    long eid = (long)cse[p0 + lm].y;
    bf16x8 af[2];
    #pragma unroll
    for (int kc = 0; kc < 2; kc++){
      const float* ap = attr + eid * BOND + kc * 32 + q * 8;
      float4 a0 = *(const float4*)ap;
      float4 a1 = *(const float4*)(ap + 4);
      U8 u;
      u.s[0] = f2bf(a0.x); u.s[1] = f2bf(a0.y); u.s[2] = f2bf(a0.z); u.s[3] = f2bf(a0.w);
      u.s[4] = f2bf(a1.x); u.s[5] = f2bf(a1.y); u.s[6] = f2bf(a1.z); u.s[7] = f2bf(a1.w);
      af[kc] = u.v;
    }
    f32x4 acc[8];
    #pragma unroll
    for (int tn = 0; tn < 8; tn++) acc[tn] = (f32x4){0.f, 0.f, 0.f, 0.f};
    #pragma unroll
    for (int kc = 0; kc < 2; kc++){
      #pragma unroll
      for (int tn = 0; tn < 8; tn++)
        acc[tn] = __builtin_amdgcn_mfma_f32_16x16x32_bf16(af[kc], bfrag[tn][kc], acc[tn], 0, 0, 0);
    }
    #pragma unroll
    for (int i = 0; i < 4; i++){
      U8 o;
      #pragma unroll
      for (int tn = 0; tn < 8; tn++) o.s[tn] = f2bf(acc[tn][i] + bias[tn]);
      *(bf16x8*)(eemb + (p0 + q * 4 + i) * (long)EMB + lm * 8) = o.v;
    }
  }
}

// ---------------- CSR build (by dst) ----------------

__global__ __launch_bounds__(256) void count_deg(const int* __restrict__ ei,
                                                 int* __restrict__ deg)
{
  int e = blockIdx.x * 256 + threadIdx.x;
  if (e < N_EDGES) atomicAdd(&deg[ei[N_EDGES + e]], 1);
}

__global__ __launch_bounds__(256) void scan_s1(const int* __restrict__ deg,
                                               int* __restrict__ blocksum)
{
  int i = blockIdx.x * 256 + threadIdx.x;
  int lane = threadIdx.x & 63, w = threadIdx.x >> 6;
  int v = (i < N_NODES) ? deg[i] : 0;
  #pragma unroll
  for (int o = 32; o > 0; o >>= 1) v += __shfl_down(v, o, 64);
  __shared__ int ws4[4];
  if (lane == 0) ws4[w] = v;
  __syncthreads();
  if (threadIdx.x == 0) blocksum[blockIdx.x] = ws4[0] + ws4[1] + ws4[2] + ws4[3];
}

__global__ __launch_bounds__(256) void scan_s2(const int* __restrict__ blocksum,
                                               int* __restrict__ blockoff,
                                               int* __restrict__ off)
{
  int t = threadIdx.x;
  int lane = t & 63, w = t >> 6;
  int v = (t < NB_SCAN) ? blocksum[t] : 0;
  int x = v;
  #pragma unroll
  for (int d = 1; d < 64; d <<= 1){
    int y = __shfl_up(x, d, 64);
    if (lane >= d) x += y;
  }
  __shared__ int wsum[4];
  if (lane == 63) wsum[w] = x;
  __syncthreads();
  int wo = 0;
  for (int j = 0; j < w; j++) wo += wsum[j];
  if (t < NB_SCAN) blockoff[t] = wo + x - v;
  if (t == 0) off[N_NODES] = wsum[0] + wsum[1] + wsum[2] + wsum[3];
}

__global__ __launch_bounds__(256) void scan_s3(const int* __restrict__ deg,
    const int* __restrict__ blockoff, int* __restrict__ off, int* __restrict__ fill)
{
  int i = blockIdx.x * 256 + threadIdx.x;
  int lane = threadIdx.x & 63, w = threadIdx.x >> 6;
  int v = (i < N_NODES) ? deg[i] : 0;
  int x = v;
  #pragma unroll
  for (int d = 1; d < 64; d <<= 1){
    int y = __shfl_up(x, d, 64);
    if (lane >= d) x += y;
  }
  __shared__ int wsum[4];
  if (lane == 63) wsum[w] = x;
  __syncthreads();
  int wo = 0;
  for (int j = 0; j < w; j++) wo += wsum[j];
  if (i < N_NODES){
    int excl = blockoff[blockIdx.x] + wo + x - v;
    off[i] = excl;
    fill[i] = excl;
  }
}

// cse[p] = {src, edge_id} — single 8B store
__global__ __launch_bounds__(256) void scatter_edges(const int* __restrict__ ei,
    int* __restrict__ fill, int2* __restrict__ cse)
{
  int e = blockIdx.x * 256 + threadIdx.x;
  if (e < N_EDGES){
    int dst = ei[N_EDGES + e];
    int p = atomicAdd(&fill[dst], 1);
    cse[p] = make_int2(ei[e], e);
  }
}

// ---------------- gather aggregation, all-bf16 node state (permuted layout) ----------------
// node_new[n] = bf16( f32(node_old[n]) + sum f32(node_old[src])*f32(eemb[p]) )
// channel-position-uniform: works identically on permuted rows.
__global__ __launch_bounds__(256) void agg_kernel(const unsigned short* __restrict__ node_old,
    const unsigned short* __restrict__ eemb, const int* __restrict__ off,
    const int2* __restrict__ cse, unsigned short* __restrict__ node_new)
{
  int n = blockIdx.x * 8 + (threadIdx.x >> 5);
  if (n >= N_NODES) return;
  int c0 = (threadIdx.x & 31) * 4;
  int s = off[n], e = off[n + 1];
  ushort4 r = *(const ushort4*)(node_old + (long)n * EMB + c0);
  float4 accA = make_float4(bf2f(r.x), bf2f(r.y), bf2f(r.z), bf2f(r.w));  // residual
  float4 accB = make_float4(0.f, 0.f, 0.f, 0.f);
  int i = s;
  for (; i + 8 <= e; i += 8){
    int idx[8];
    #pragma unroll
    for (int j = 0; j < 8; j++) idx[j] = cse[i + j].x;
    ushort4 a[8], eb[8];
    #pragma unroll
    for (int j = 0; j < 8; j++){
      a[j]  = *(const ushort4*)(node_old + (long)idx[j] * EMB + c0);
      eb[j] = *(const ushort4*)(eemb + (long)(i + j) * EMB + c0);
    }
    #pragma unroll
    for (int j = 0; j < 8; j++){
      float4& acc = (j & 1) ? accB : accA;
      acc.x = fmaf(bf2f(a[j].x), bf2f(eb[j].x), acc.x);
      acc.y = fmaf(bf2f(a[j].y), bf2f(eb[j].y), acc.y);
      acc.z = fmaf(bf2f(a[j].z), bf2f(eb[j].z), acc.z);
      acc.w = fmaf(bf2f(a[j].w), bf2f(eb[j].w), acc.w);
    }
  }
  for (; i < e; i++){
    int src = cse[i].x;
    ushort4 a  = *(const ushort4*)(node_old + (long)src * EMB + c0);
    ushort4 eb = *(const ushort4*)(eemb + (long)i * EMB + c0);
    accA.x = fmaf(bf2f(a.x), bf2f(eb.x), accA.x);
    accA.y = fmaf(bf2f(a.y), bf2f(eb.y), accA.y);
    accA.z = fmaf(bf2f(a.z), bf2f(eb.z), accA.z);
    accA.w = fmaf(bf2f(a.w), bf2f(eb.w), accA.w);
  }
  ushort4 o;
  o.x = f2bf(accA.x + accB.x);
  o.y = f2bf(accA.y + accB.y);
  o.z = f2bf(accA.z + accB.z);
  o.w = f2bf(accA.w + accB.w);
  *(ushort4*)(node_new + (long)n * EMB + c0) = o;
}

// ---------------- fused MFMA MLP + block-pooled reduction (permuted bf16 input) ----------------
// Input rows are sigma-permuted; w1bf's K dim is permuted to match (prep_w).
// h1 onward is standard channel space.
__global__ __launch_bounds__(256) void mlp_mfma_pool(const unsigned short* __restrict__ ne,
    const unsigned short* __restrict__ w1bf, const unsigned short* __restrict__ w2bf,
    const float* __restrict__ b1, const float* __restrict__ b2,
    const float* __restrict__ W3, const int* __restrict__ batch,
    float* __restrict__ dg)
{
  __shared__ float h1s[4][16 * 132];   // per-wave scratch
  __shared__ float pool[NGRAPH];       // per-block graph accumulator
  const int t = threadIdx.x;
  const int wv = t >> 6, l = t & 63;
  const int lm = l & 15, q = l >> 4;
  union U8 { bf16x8 v; unsigned short s[8]; };

  for (int i = t; i < NGRAPH; i += 256) pool[i] = 0.f;
  __syncthreads();

  const int strip = blockIdx.x * 4 + wv;
  if (strip < NSTRIP){
    const long n0 = (long)strip * 16;

    float b1v[8], b2v[4], w3v[4];
    #pragma unroll
    for (int tn = 0; tn < 8; tn++) b1v[tn] = b1[tn * 16 + lm];
    #pragma unroll
    for (int tc = 0; tc < 4; tc++){ b2v[tc] = b2[tc * 16 + lm]; w3v[tc] = W3[tc * 16 + lm]; }

    // A-fragments: direct bf16 16B loads + sign-bit relu (positions permuted; W1 compensates)
    bf16x8 a1[4];
    #pragma unroll
    for (int kc = 0; kc < 4; kc++){
      const unsigned short* ap = ne + (n0 + lm) * (long)EMB + kc * 32 + q * 8;
      ushort4 v0 = *(const ushort4*)ap;
      ushort4 v1 = *(const ushort4*)(ap + 4);
      U8 u;
      u.s[0] = brelu(v0.x); u.s[1] = brelu(v0.y); u.s[2] = brelu(v0.z); u.s[3] = brelu(v0.w);
      u.s[4] = brelu(v1.x); u.s[5] = brelu(v1.y); u.s[6] = brelu(v1.z); u.s[7] = brelu(v1.w);
      a1[kc] = u.v;
    }

    f32x4 acc1[8];
    #pragma unroll
    for (int tn = 0; tn < 8; tn++) acc1[tn] = (f32x4){b1v[tn], b1v[tn], b1v[tn], b1v[tn]};
    #pragma unroll
    for (int kc = 0; kc < 4; kc++){
      #pragma unroll
      for (int tn = 0; tn < 8; tn++){
        bf16x8 bf = *(const bf16x8*)(w1bf + (size_t)((tn * 4 + kc) * 64 + l) * 8);
        acc1[tn] = __builtin_amdgcn_mfma_f32_16x16x32_bf16(a1[kc], bf, acc1[tn], 0, 0, 0);
      }
    }

    float* h1 = h1s[wv];
    #pragma unroll
    for (int tn = 0; tn < 8; tn++)
      #pragma unroll
      for (int i = 0; i < 4; i++)
        h1[(q * 4 + i) * 132 + tn * 16 + lm] = fmaxf(acc1[tn][i], 0.f);
    bf16x8 a2[4];
    #pragma unroll
    for (int kc = 0; kc < 4; kc++){
      const float* hp = h1 + lm * 132 + kc * 32 + q * 8;
      float4 x0 = *(const float4*)hp;
      float4 x1 = *(const float4*)(hp + 4);
      U8 u;
      u.s[0] = f2bf(x0.x); u.s[1] = f2bf(x0.y); u.s[2] = f2bf(x0.z); u.s[3] = f2bf(x0.w);
      u.s[4] = f2bf(x1.x); u.s[5] = f2bf(x1.y); u.s[6] = f2bf(x1.z); u.s[7] = f2bf(x1.w);
      a2[kc] = u.v;
    }

    f32x4 acc2[4];
    #pragma unroll
    for (int tc = 0; tc < 4; tc++) acc2[tc] = (f32x4){b2v[tc], b2v[tc], b2v[tc], b2v[tc]};
    #pragma unroll
    for (int kc = 0; kc < 4; kc++){
      #pragma unroll
      for (int tc = 0; tc < 4; tc++){
        bf16x8 bf = *(const bf16x8*)(w2bf + (size_t)((tc * 4 + kc) * 64 + l) * 8);
        acc2[tc] = __builtin_amdgcn_mfma_f32_16x16x32_bf16(a2[kc], bf, acc2[tc], 0, 0, 0);
      }
    }

    float e4[4];
    #pragma unroll
    for (int i = 0; i < 4; i++){
      float s = 0.f;
      #pragma unroll
      for (int tc = 0; tc < 4; tc++) s = fmaf(fmaxf(acc2[tc][i], 0.f), w3v[tc], s);
      e4[i] = s;
    }
    #pragma unroll
    for (int m = 1; m < 16; m <<= 1)
      #pragma unroll
      for (int i = 0; i < 4; i++) e4[i] += __shfl_xor(e4[i], m, 64);
    if (lm == 0){
      #pragma unroll
      for (int i = 0; i < 4; i++){
        int node = (int)n0 + q * 4 + i;
        atomicAdd(&pool[batch[node]], e4[i]);
      }
    }
  }
  __syncthreads();
  for (int i = t; i < NGRAPH; i += 256){
    float v = pool[i];
    if (v != 0.f) atomicAdd(&dg[i], v);
  }
}

extern "C" void kernel_launch(void* const* d_in, const int* in_sizes, int n_in,
                              void* d_out, int out_size, void* d_ws, size_t ws_size,
                              hipStream_t stream)
{
  const float* x         = (const float*)d_in[0];
  const float* edge_attr = (const float*)d_in[1];
  const int*   ei        = (const int*)d_in[2];   // [2][E]: row0=src, row1=dst
  const int*   batch     = (const int*)d_in[3];
  const float* Wa = (const float*)d_in[4];
  const float* ba = (const float*)d_in[5];
  const float* Wb = (const float*)d_in[6];
  const float* bb = (const float*)d_in[7];
  const float* W1 = (const float*)d_in[8];
  const float* b1 = (const float*)d_in[9];
  const float* W2 = (const float*)d_in[10];
  const float* b2 = (const float*)d_in[11];
  const float* W3 = (const float*)d_in[12];

  char* ws = (char*)d_ws;
  size_t p = 0;
  auto alloc = [&](size_t bytes) -> char* {
    char* q = ws + p;
    p += (bytes + 255) & ~(size_t)255;
    return q;
  };
  unsigned short* bufA = (unsigned short*)alloc((size_t)N_NODES * EMB * 2);    // 12.8 MB
  unsigned short* bufB = (unsigned short*)alloc((size_t)N_NODES * EMB * 2);    // 12.8 MB
  unsigned short* eemb = (unsigned short*)alloc((size_t)N_EDGES * EMB * 2);    // 128 MB
  unsigned short* wabf = (unsigned short*)alloc(16384 * sizeof(short));
  unsigned short* w1bf = (unsigned short*)alloc(16384 * sizeof(short));
  unsigned short* w2bf = (unsigned short*)alloc(8192 * sizeof(short));
  unsigned short* wbbf = (unsigned short*)alloc(8192 * sizeof(short));
  int* deg  = (int*)alloc(N_NODES * sizeof(int));
  int* off  = (int*)alloc((N_NODES + 1) * sizeof(int));
  int* fill = (int*)alloc(N_NODES * sizeof(int));
  int* blocksum = (int*)alloc(NB_SCAN * sizeof(int));
  int* blockoff = (int*)alloc(NB_SCAN * sizeof(int));
  int2* cse = (int2*)alloc((size_t)N_EDGES * sizeof(int2));                    // 4 MB
  if (p > ws_size){
    fprintf(stderr, "kernel_launch: ws too small (%zu < %zu)\n", ws_size, p);
    return;
  }

  // CSR build
  hipMemsetAsync(deg, 0, N_NODES * sizeof(int), stream);
  count_deg<<<(N_EDGES + 255) / 256, 256, 0, stream>>>(ei, deg);
  scan_s1<<<NB_SCAN, 256, 0, stream>>>(deg, blocksum);
  scan_s2<<<1, 256, 0, stream>>>(blocksum, blockoff, off);
  scan_s3<<<NB_SCAN, 256, 0, stream>>>(deg, blockoff, off, fill);
  scatter_edges<<<(N_EDGES + 255) / 256, 256, 0, stream>>>(ei, fill, cse);

  // Embeddings (both MFMA; permuted bf16 rows, no LDS transform)
  prep_w<<<192, 256, 0, stream>>>(Wa, W1, W2, Wb, wabf, w1bf, w2bf, wbbf);
  node_gemm_mfma<<<(NSTRIP + 3) / 4, 256, 0, stream>>>(x, wabf, ba, bufA);
  edge_gemm_mfma<<<2048, 256, 0, stream>>>(edge_attr, wbbf, bb, cse, eemb);

  // Two message-passing layers, gather-based, residual fused, bf16 state
  agg_kernel<<<(N_NODES + 7) / 8, 256, 0, stream>>>(bufA, eemb, off, cse, bufB);
  agg_kernel<<<(N_NODES + 7) / 8, 256, 0, stream>>>(bufB, eemb, off, cse, bufA);

  // Fused MFMA MLP + pool
  hipMemsetAsync(d_out, 0, NGRAPH * sizeof(float), stream);
  mlp_mfma_pool<<<(NSTRIP + 3) / 4, 256, 0, stream>>>(bufA, w1bf, w2bf, b1, b2, W3, batch, (float*)d_out);
}

// Round 2
// 416.672 us; speedup vs baseline: 1.0425x; 1.0275x over previous
//
#include <hip/hip_runtime.h>
#include <cstdio>
#include <cstdint>

#define N_NODES 50000
#define N_EDGES 500000
#define EMB 128
#define BOND 64
#define NGRAPH 256
#define NB_SCAN ((N_NODES + 255) / 256)   // 196 scan blocks
#define NSTRIP (N_NODES / 16)             // 3125 exact 16-node strips
#define ESTRIP (N_EDGES / 16)             // 31250 exact 16-edge strips

typedef short bf16x8 __attribute__((ext_vector_type(8)));   // 8 bf16 (4 VGPRs)
typedef float f32x4  __attribute__((ext_vector_type(4)));

__device__ __forceinline__ unsigned short f2bf(float v){
  unsigned u = __float_as_uint(v);
  unsigned r = (u + 0x7fffu + ((u >> 16) & 1u)) >> 16;  // RNE
  return (unsigned short)r;
}
__device__ __forceinline__ float bf2f(unsigned short u){
  return __uint_as_float(((unsigned)u) << 16);
}
__device__ __forceinline__ unsigned short brelu(unsigned short u){
  return (u & 0x8000u) ? (unsigned short)0 : u;   // bf16 relu: sign bit -> 0
}

// ---------------------------------------------------------------------------
// Channel permutation: node/edge embedding rows are stored in MFMA-fragment
// order. Stored position p holds TRUE channel sigma(p) = (p&7)*16 + (p>>3).
// agg_kernel (elementwise mul + per-channel sum + residual) is permutation-
// invariant; the MLP compensates by permuting W1's K dimension in prep_w.
//
// R2: edge GEMM reads attr LINEARLY (edge-id order) and scatter-writes eemb
// rows to CSR slots via pos[e] (inverse permutation from scatter_edges).
// Removes the random-gather latency chain entirely.
// ---------------------------------------------------------------------------

// weight prep: fragment-linear bf16 for Wa, W1 (K-permuted), W2, Wb
__global__ void prep_w(const float* __restrict__ Wa, const float* __restrict__ W1,
                       const float* __restrict__ W2, const float* __restrict__ Wb,
                       unsigned short* __restrict__ wabf, unsigned short* __restrict__ w1bf,
                       unsigned short* __restrict__ w2bf, unsigned short* __restrict__ wbbf)
{
  int i = blockIdx.x * 256 + threadIdx.x;
  if (i < 40960){
    int i2 = i & 16383;
    int j = i2 & 7, lb = (i2 >> 3) & 63, kc = (i2 >> 9) & 3, tn = i2 >> 11;
    int lm = lb & 15, q = lb >> 4;
    int row = tn * 16 + lm, col = kc * 32 + q * 8 + j;
    if (i < 16384){
      wabf[i] = f2bf(Wa[row * EMB + col]);                 // K = raw atom dim, unpermuted
    } else if (i < 32768){
      int pcol = j * 16 + kc * 4 + q;                      // sigma(col): match permuted node layout
      w1bf[i2] = f2bf(W1[row * EMB + pcol]);
    } else {
      w2bf[i2] = f2bf(W2[row * EMB + col]);                // h1 is standard layout; tn in [0,4)
    }
  } else if (i < 49152){
    int i2 = i - 40960;                                    // Wb: [8 tn][2 kc][64 l][8 j]
    int j = i2 & 7, l = (i2 >> 3) & 63, kc = (i2 >> 9) & 1, tn = i2 >> 10;
    int lm = l & 15, q = l >> 4;
    wbbf[i2] = f2bf(Wb[(tn * 16 + lm) * BOND + kc * 32 + q * 8 + j]);
  }
}

// ---------------- bf16 MFMA node-embedding GEMM, direct fragment store ----------------
__global__ __launch_bounds__(256) void node_gemm_mfma(const float* __restrict__ x,
    const unsigned short* __restrict__ wabf, const float* __restrict__ ba,
    unsigned short* __restrict__ out)
{
  const int t = threadIdx.x;
  const int wv = t >> 6, l = t & 63;
  const int lm = l & 15, q = l >> 4;
  union U8 { bf16x8 v; unsigned short s[8]; };
  const int strip = blockIdx.x * 4 + wv;
  if (strip >= NSTRIP) return;
  const long n0 = (long)strip * 16;

  bf16x8 a[4];
  #pragma unroll
  for (int kc = 0; kc < 4; kc++){
    const float* ap = x + (n0 + lm) * (long)EMB + kc * 32 + q * 8;
    float4 x0 = *(const float4*)ap;
    float4 x1 = *(const float4*)(ap + 4);
    U8 u;
    u.s[0] = f2bf(x0.x); u.s[1] = f2bf(x0.y); u.s[2] = f2bf(x0.z); u.s[3] = f2bf(x0.w);
    u.s[4] = f2bf(x1.x); u.s[5] = f2bf(x1.y); u.s[6] = f2bf(x1.z); u.s[7] = f2bf(x1.w);
    a[kc] = u.v;
  }
  float biasv[8];
  #pragma unroll
  for (int tn = 0; tn < 8; tn++) biasv[tn] = ba[tn * 16 + lm];

  f32x4 acc[8];
  #pragma unroll
  for (int tn = 0; tn < 8; tn++) acc[tn] = (f32x4){0.f, 0.f, 0.f, 0.f};
  #pragma unroll
  for (int kc = 0; kc < 4; kc++){
    #pragma unroll
    for (int tn = 0; tn < 8; tn++){
      bf16x8 bf = *(const bf16x8*)(wabf + (size_t)((tn * 4 + kc) * 64 + l) * 8);
      acc[tn] = __builtin_amdgcn_mfma_f32_16x16x32_bf16(a[kc], bf, acc[tn], 0, 0, 0);
    }
  }
  // direct permuted store: row n0+q*4+i, positions lm*8+tn hold channel tn*16+lm
  #pragma unroll
  for (int i = 0; i < 4; i++){
    U8 o;
    #pragma unroll
    for (int tn = 0; tn < 8; tn++) o.s[tn] = f2bf(acc[tn][i] + biasv[tn]);
    *(bf16x8*)(out + (n0 + q * 4 + i) * (long)EMB + lm * 8) = o.v;
  }
}

// ---------------- bf16 MFMA edge GEMM: LINEAR attr read, scatter store via pos ---------
// R2: no gather. Lane lm's A-row is edge e0+lm (contiguous 4KB per wave-iter).
// C rows (edges e0+q*4+i) scatter-store to CSR slot pos[e0+q*4+i].
__global__ __launch_bounds__(256) void edge_gemm_mfma(
    const float* __restrict__ attr, const unsigned short* __restrict__ wbbf,
    const float* __restrict__ bb, const int* __restrict__ pos,
    unsigned short* __restrict__ eemb)
{
  const int t = threadIdx.x;
  const int l = t & 63;
  const int lm = l & 15, q = l >> 4;
  union U8 { bf16x8 v; unsigned short s[8]; };

  bf16x8 bfrag[8][2];
  float bias[8];
  #pragma unroll
  for (int tn = 0; tn < 8; tn++){
    bias[tn] = bb[tn * 16 + lm];
    #pragma unroll
    for (int kc = 0; kc < 2; kc++)
      bfrag[tn][kc] = *(const bf16x8*)(wbbf + (size_t)((tn * 2 + kc) * 64 + l) * 8);
  }

  const long wid = (long)blockIdx.x * 4 + (t >> 6);
  const long stride = (long)gridDim.x * 4 * 16;
  for (long e0 = wid * 16; e0 < N_EDGES; e0 += stride){
    // CSR slots for the 4 output rows this lane stores (16B broadcast per q-group)
    int4 pv = *(const int4*)(pos + e0 + q * 4);
    bf16x8 af[2];
    #pragma unroll
    for (int kc = 0; kc < 2; kc++){
      const float* ap = attr + (e0 + lm) * (long)BOND + kc * 32 + q * 8;
      float4 a0 = *(const float4*)ap;
      float4 a1 = *(const float4*)(ap + 4);
      U8 u;
      u.s[0] = f2bf(a0.x); u.s[1] = f2bf(a0.y); u.s[2] = f2bf(a0.z); u.s[3] = f2bf(a0.w);
      u.s[4] = f2bf(a1.x); u.s[5] = f2bf(a1.y); u.s[6] = f2bf(a1.z); u.s[7] = f2bf(a1.w);
      af[kc] = u.v;
    }
    f32x4 acc[8];
    #pragma unroll
    for (int tn = 0; tn < 8; tn++) acc[tn] = (f32x4){0.f, 0.f, 0.f, 0.f};
    #pragma unroll
    for (int kc = 0; kc < 2; kc++){
      #pragma unroll
      for (int tn = 0; tn < 8; tn++)
        acc[tn] = __builtin_amdgcn_mfma_f32_16x16x32_bf16(af[kc], bfrag[tn][kc], acc[tn], 0, 0, 0);
    }
    int pr[4] = {pv.x, pv.y, pv.z, pv.w};
    #pragma unroll
    for (int i = 0; i < 4; i++){
      U8 o;
      #pragma unroll
      for (int tn = 0; tn < 8; tn++) o.s[tn] = f2bf(acc[tn][i] + bias[tn]);
      *(bf16x8*)(eemb + (long)pr[i] * EMB + lm * 8) = o.v;
    }
  }
}

// ---------------- CSR build (by dst) ----------------

__global__ __launch_bounds__(256) void count_deg(const int* __restrict__ ei,
                                                 int* __restrict__ deg)
{
  int e = blockIdx.x * 256 + threadIdx.x;
  if (e < N_EDGES) atomicAdd(&deg[ei[N_EDGES + e]], 1);
}

__global__ __launch_bounds__(256) void scan_s1(const int* __restrict__ deg,
                                               int* __restrict__ blocksum)
{
  int i = blockIdx.x * 256 + threadIdx.x;
  int lane = threadIdx.x & 63, w = threadIdx.x >> 6;
  int v = (i < N_NODES) ? deg[i] : 0;
  #pragma unroll
  for (int o = 32; o > 0; o >>= 1) v += __shfl_down(v, o, 64);
  __shared__ int ws4[4];
  if (lane == 0) ws4[w] = v;
  __syncthreads();
  if (threadIdx.x == 0) blocksum[blockIdx.x] = ws4[0] + ws4[1] + ws4[2] + ws4[3];
}

__global__ __launch_bounds__(256) void scan_s2(const int* __restrict__ blocksum,
                                               int* __restrict__ blockoff,
                                               int* __restrict__ off)
{
  int t = threadIdx.x;
  int lane = t & 63, w = t >> 6;
  int v = (t < NB_SCAN) ? blocksum[t] : 0;
  int x = v;
  #pragma unroll
  for (int d = 1; d < 64; d <<= 1){
    int y = __shfl_up(x, d, 64);
    if (lane >= d) x += y;
  }
  __shared__ int wsum[4];
  if (lane == 63) wsum[w] = x;
  __syncthreads();
  int wo = 0;
  for (int j = 0; j < w; j++) wo += wsum[j];
  if (t < NB_SCAN) blockoff[t] = wo + x - v;
  if (t == 0) off[N_NODES] = wsum[0] + wsum[1] + wsum[2] + wsum[3];
}

__global__ __launch_bounds__(256) void scan_s3(const int* __restrict__ deg,
    const int* __restrict__ blockoff, int* __restrict__ off, int* __restrict__ fill)
{
  int i = blockIdx.x * 256 + threadIdx.x;
  int lane = threadIdx.x & 63, w = threadIdx.x >> 6;
  int v = (i < N_NODES) ? deg[i] : 0;
  int x = v;
  #pragma unroll
  for (int d = 1; d < 64; d <<= 1){
    int y = __shfl_up(x, d, 64);
    if (lane >= d) x += y;
  }
  __shared__ int wsum[4];
  if (lane == 63) wsum[w] = x;
  __syncthreads();
  int wo = 0;
  for (int j = 0; j < w; j++) wo += wsum[j];
  if (i < N_NODES){
    int excl = blockoff[blockIdx.x] + wo + x - v;
    off[i] = excl;
    fill[i] = excl;
  }
}

// cse[p] = {src, edge_id}; pos[e] = p (inverse permutation for scatter-store GEMM)
__global__ __launch_bounds__(256) void scatter_edges(const int* __restrict__ ei,
    int* __restrict__ fill, int2* __restrict__ cse, int* __restrict__ pos)
{
  int e = blockIdx.x * 256 + threadIdx.x;
  if (e < N_EDGES){
    int dst = ei[N_EDGES + e];
    int p = atomicAdd(&fill[dst], 1);
    cse[p] = make_int2(ei[e], e);
    pos[e] = p;
  }
}

// ---------------- gather aggregation, all-bf16 node state (permuted layout) ----------------
// node_new[n] = bf16( f32(node_old[n]) + sum f32(node_old[src])*f32(eemb[p]) )
// R2: 8/4/2/1 unroll ladder — caps serial tail latency at 3 grouped steps.
__global__ __launch_bounds__(256) void agg_kernel(const unsigned short* __restrict__ node_old,
    const unsigned short* __restrict__ eemb, const int* __restrict__ off,
    const int2* __restrict__ cse, unsigned short* __restrict__ node_new)
{
  int n = blockIdx.x * 8 + (threadIdx.x >> 5);
  if (n >= N_NODES) return;
  int c0 = (threadIdx.x & 31) * 4;
  int s = off[n], e = off[n + 1];
  ushort4 r = *(const ushort4*)(node_old + (long)n * EMB + c0);
  float4 accA = make_float4(bf2f(r.x), bf2f(r.y), bf2f(r.z), bf2f(r.w));  // residual
  float4 accB = make_float4(0.f, 0.f, 0.f, 0.f);
  int i = s;

#define AGG_BLOCK(CNT)                                                        \
  {                                                                           \
    int idx[CNT];                                                             \
    _Pragma("unroll")                                                         \
    for (int j = 0; j < CNT; j++) idx[j] = cse[i + j].x;                      \
    ushort4 a[CNT], eb[CNT];                                                  \
    _Pragma("unroll")                                                         \
    for (int j = 0; j < CNT; j++){                                            \
      a[j]  = *(const ushort4*)(node_old + (long)idx[j] * EMB + c0);          \
      eb[j] = *(const ushort4*)(eemb + (long)(i + j) * EMB + c0);             \
    }                                                                         \
    _Pragma("unroll")                                                         \
    for (int j = 0; j < CNT; j++){                                            \
      float4& acc = (j & 1) ? accB : accA;                                    \
      acc.x = fmaf(bf2f(a[j].x), bf2f(eb[j].x), acc.x);                       \
      acc.y = fmaf(bf2f(a[j].y), bf2f(eb[j].y), acc.y);                       \
      acc.z = fmaf(bf2f(a[j].z), bf2f(eb[j].z), acc.z);                       \
      acc.w = fmaf(bf2f(a[j].w), bf2f(eb[j].w), acc.w);                       \
    }                                                                         \
    i += CNT;                                                                 \
  }

  for (; i + 8 <= e; ) AGG_BLOCK(8)
  if (i + 4 <= e) AGG_BLOCK(4)
  if (i + 2 <= e) AGG_BLOCK(2)
  if (i < e) AGG_BLOCK(1)
#undef AGG_BLOCK

  ushort4 o;
  o.x = f2bf(accA.x + accB.x);
  o.y = f2bf(accA.y + accB.y);
  o.z = f2bf(accA.z + accB.z);
  o.w = f2bf(accA.w + accB.w);
  *(ushort4*)(node_new + (long)n * EMB + c0) = o;
}

// ---------------- fused MFMA MLP + block-pooled reduction (permuted bf16 input) ----------------
__global__ __launch_bounds__(256) void mlp_mfma_pool(const unsigned short* __restrict__ ne,
    const unsigned short* __restrict__ w1bf, const unsigned short* __restrict__ w2bf,
    const float* __restrict__ b1, const float* __restrict__ b2,
    const float* __restrict__ W3, const int* __restrict__ batch,
    float* __restrict__ dg)
{
  __shared__ float h1s[4][16 * 132];   // per-wave scratch
  __shared__ float pool[NGRAPH];       // per-block graph accumulator
  const int t = threadIdx.x;
  const int wv = t >> 6, l = t & 63;
  const int lm = l & 15, q = l >> 4;
  union U8 { bf16x8 v; unsigned short s[8]; };

  for (int i = t; i < NGRAPH; i += 256) pool[i] = 0.f;
  __syncthreads();

  const int strip = blockIdx.x * 4 + wv;
  if (strip < NSTRIP){
    const long n0 = (long)strip * 16;

    float b1v[8], b2v[4], w3v[4];
    #pragma unroll
    for (int tn = 0; tn < 8; tn++) b1v[tn] = b1[tn * 16 + lm];
    #pragma unroll
    for (int tc = 0; tc < 4; tc++){ b2v[tc] = b2[tc * 16 + lm]; w3v[tc] = W3[tc * 16 + lm]; }

    // A-fragments: direct bf16 16B loads + sign-bit relu (positions permuted; W1 compensates)
    bf16x8 a1[4];
    #pragma unroll
    for (int kc = 0; kc < 4; kc++){
      const unsigned short* ap = ne + (n0 + lm) * (long)EMB + kc * 32 + q * 8;
      ushort4 v0 = *(const ushort4*)ap;
      ushort4 v1 = *(const ushort4*)(ap + 4);
      U8 u;
      u.s[0] = brelu(v0.x); u.s[1] = brelu(v0.y); u.s[2] = brelu(v0.z); u.s[3] = brelu(v0.w);
      u.s[4] = brelu(v1.x); u.s[5] = brelu(v1.y); u.s[6] = brelu(v1.z); u.s[7] = brelu(v1.w);
      a1[kc] = u.v;
    }

    f32x4 acc1[8];
    #pragma unroll
    for (int tn = 0; tn < 8; tn++) acc1[tn] = (f32x4){b1v[tn], b1v[tn], b1v[tn], b1v[tn]};
    #pragma unroll
    for (int kc = 0; kc < 4; kc++){
      #pragma unroll
      for (int tn = 0; tn < 8; tn++){
        bf16x8 bf = *(const bf16x8*)(w1bf + (size_t)((tn * 4 + kc) * 64 + l) * 8);
        acc1[tn] = __builtin_amdgcn_mfma_f32_16x16x32_bf16(a1[kc], bf, acc1[tn], 0, 0, 0);
      }
    }

    float* h1 = h1s[wv];
    #pragma unroll
    for (int tn = 0; tn < 8; tn++)
      #pragma unroll
      for (int i = 0; i < 4; i++)
        h1[(q * 4 + i) * 132 + tn * 16 + lm] = fmaxf(acc1[tn][i], 0.f);
    bf16x8 a2[4];
    #pragma unroll
    for (int kc = 0; kc < 4; kc++){
      const float* hp = h1 + lm * 132 + kc * 32 + q * 8;
      float4 x0 = *(const float4*)hp;
      float4 x1 = *(const float4*)(hp + 4);
      U8 u;
      u.s[0] = f2bf(x0.x); u.s[1] = f2bf(x0.y); u.s[2] = f2bf(x0.z); u.s[3] = f2bf(x0.w);
      u.s[4] = f2bf(x1.x); u.s[5] = f2bf(x1.y); u.s[6] = f2bf(x1.z); u.s[7] = f2bf(x1.w);
      a2[kc] = u.v;
    }

    f32x4 acc2[4];
    #pragma unroll
    for (int tc = 0; tc < 4; tc++) acc2[tc] = (f32x4){b2v[tc], b2v[tc], b2v[tc], b2v[tc]};
    #pragma unroll
    for (int kc = 0; kc < 4; kc++){
      #pragma unroll
      for (int tc = 0; tc < 4; tc++){
        bf16x8 bf = *(const bf16x8*)(w2bf + (size_t)((tc * 4 + kc) * 64 + l) * 8);
        acc2[tc] = __builtin_amdgcn_mfma_f32_16x16x32_bf16(a2[kc], bf, acc2[tc], 0, 0, 0);
      }
    }

    float e4[4];
    #pragma unroll
    for (int i = 0; i < 4; i++){
      float s = 0.f;
      #pragma unroll
      for (int tc = 0; tc < 4; tc++) s = fmaf(fmaxf(acc2[tc][i], 0.f), w3v[tc], s);
      e4[i] = s;
    }
    #pragma unroll
    for (int m = 1; m < 16; m <<= 1)
      #pragma unroll
      for (int i = 0; i < 4; i++) e4[i] += __shfl_xor(e4[i], m, 64);
    if (lm == 0){
      #pragma unroll
      for (int i = 0; i < 4; i++){
        int node = (int)n0 + q * 4 + i;
        atomicAdd(&pool[batch[node]], e4[i]);
      }
    }
  }
  __syncthreads();
  for (int i = t; i < NGRAPH; i += 256){
    float v = pool[i];
    if (v != 0.f) atomicAdd(&dg[i], v);
  }
}

extern "C" void kernel_launch(void* const* d_in, const int* in_sizes, int n_in,
                              void* d_out, int out_size, void* d_ws, size_t ws_size,
                              hipStream_t stream)
{
  const float* x         = (const float*)d_in[0];
  const float* edge_attr = (const float*)d_in[1];
  const int*   ei        = (const int*)d_in[2];   // [2][E]: row0=src, row1=dst
  const int*   batch     = (const int*)d_in[3];
  const float* Wa = (const float*)d_in[4];
  const float* ba = (const float*)d_in[5];
  const float* Wb = (const float*)d_in[6];
  const float* bb = (const float*)d_in[7];
  const float* W1 = (const float*)d_in[8];
  const float* b1 = (const float*)d_in[9];
  const float* W2 = (const float*)d_in[10];
  const float* b2 = (const float*)d_in[11];
  const float* W3 = (const float*)d_in[12];

  char* ws = (char*)d_ws;
  size_t p = 0;
  auto alloc = [&](size_t bytes) -> char* {
    char* q = ws + p;
    p += (bytes + 255) & ~(size_t)255;
    return q;
  };
  unsigned short* bufA = (unsigned short*)alloc((size_t)N_NODES * EMB * 2);    // 12.8 MB
  unsigned short* bufB = (unsigned short*)alloc((size_t)N_NODES * EMB * 2);    // 12.8 MB
  unsigned short* eemb = (unsigned short*)alloc((size_t)N_EDGES * EMB * 2);    // 128 MB
  unsigned short* wabf = (unsigned short*)alloc(16384 * sizeof(short));
  unsigned short* w1bf = (unsigned short*)alloc(16384 * sizeof(short));
  unsigned short* w2bf = (unsigned short*)alloc(8192 * sizeof(short));
  unsigned short* wbbf = (unsigned short*)alloc(8192 * sizeof(short));
  int* deg  = (int*)alloc(N_NODES * sizeof(int));
  int* off  = (int*)alloc((N_NODES + 1) * sizeof(int));
  int* fill = (int*)alloc(N_NODES * sizeof(int));
  int* blocksum = (int*)alloc(NB_SCAN * sizeof(int));
  int* blockoff = (int*)alloc(NB_SCAN * sizeof(int));
  int2* cse = (int2*)alloc((size_t)N_EDGES * sizeof(int2));                    // 4 MB
  int* pos  = (int*)alloc((size_t)N_EDGES * sizeof(int));                      // 2 MB
  if (p > ws_size){
    fprintf(stderr, "kernel_launch: ws too small (%zu < %zu)\n", ws_size, p);
    return;
  }

  // CSR build
  hipMemsetAsync(deg, 0, N_NODES * sizeof(int), stream);
  count_deg<<<(N_EDGES + 255) / 256, 256, 0, stream>>>(ei, deg);
  scan_s1<<<NB_SCAN, 256, 0, stream>>>(deg, blocksum);
  scan_s2<<<1, 256, 0, stream>>>(blocksum, blockoff, off);
  scan_s3<<<NB_SCAN, 256, 0, stream>>>(deg, blockoff, off, fill);
  scatter_edges<<<(N_EDGES + 255) / 256, 256, 0, stream>>>(ei, fill, cse, pos);

  // Embeddings (both MFMA; permuted bf16 rows; edge GEMM streams attr linearly)
  prep_w<<<192, 256, 0, stream>>>(Wa, W1, W2, Wb, wabf, w1bf, w2bf, wbbf);
  node_gemm_mfma<<<(NSTRIP + 3) / 4, 256, 0, stream>>>(x, wabf, ba, bufA);
  edge_gemm_mfma<<<2048, 256, 0, stream>>>(edge_attr, wbbf, bb, pos, eemb);

  // Two message-passing layers, gather-based, residual fused, bf16 state
  agg_kernel<<<(N_NODES + 7) / 8, 256, 0, stream>>>(bufA, eemb, off, cse, bufB);
  agg_kernel<<<(N_NODES + 7) / 8, 256, 0, stream>>>(bufB, eemb, off, cse, bufA);

  // Fused MFMA MLP + pool
  hipMemsetAsync(d_out, 0, NGRAPH * sizeof(float), stream);
  mlp_mfma_pool<<<(NSTRIP + 3) / 4, 256, 0, stream>>>(bufA, w1bf, w2bf, b1, b2, W3, batch, (float*)d_out);
}